// Round 10
// baseline (89.564 us; speedup 1.0000x reference)
//
#include <hip/hip_runtime.h>

typedef float  f32x4  __attribute__((ext_vector_type(4)));
typedef short  s16x8  __attribute__((ext_vector_type(8)));
typedef short  s16x4  __attribute__((ext_vector_type(4)));

__device__ __forceinline__ unsigned short f2bf(float f) {
    unsigned int u = __float_as_uint(f);
    return (unsigned short)((u + 0x7FFFu + ((u >> 16) & 1u)) >> 16);
}

__device__ __forceinline__ s16x8 cvt8(f32x4 a, f32x4 b) {
    union { unsigned int u[4]; s16x8 v; } r;
    asm("v_cvt_pk_bf16_f32 %0, %1, %2" : "=v"(r.u[0]) : "v"(a[0]), "v"(a[1]));
    asm("v_cvt_pk_bf16_f32 %0, %1, %2" : "=v"(r.u[1]) : "v"(a[2]), "v"(a[3]));
    asm("v_cvt_pk_bf16_f32 %0, %1, %2" : "=v"(r.u[2]) : "v"(b[0]), "v"(b[1]));
    asm("v_cvt_pk_bf16_f32 %0, %1, %2" : "=v"(r.u[3]) : "v"(b[2]), "v"(b[3]));
    return r.v;
}

#define GLOAD_LDS16(g, l) __builtin_amdgcn_global_load_lds(                    \
    (const __attribute__((address_space(1))) void*)(g),                        \
    (__attribute__((address_space(3))) void*)(l), 16, 0, 0)

// ---------------------------------------------------------------------------
// Kernel 0: wt2 = swizzle-tiled bf16 weights (verified in R6/R7):
// 16 K-tiles of [384][128B], row-XOR-swizzled so linear global_load_lds
// reproduces the conflict-free LDS layout.
// ---------------------------------------------------------------------------
__global__ void prep_wt(const float* __restrict__ Wq,
                        const float* __restrict__ Wk,
                        const float* __restrict__ Wv,
                        unsigned char* __restrict__ wt2) {
    int n = blockIdx.x;                       // 0..383
    const float* W = (n < 128) ? Wq : ((n < 256) ? Wk : Wv);
    int h = n & 127;
    for (int k = threadIdx.x; k < 1024; k += blockDim.x) {
        unsigned short v = f2bf(W[(size_t)k * 128 + h]);
        size_t off = (size_t)(k >> 6) * 49152 + (size_t)n * 128 +
                     (((k & 63) * 2) ^ ((n & 7) << 4));
        *(unsigned short*)(wt2 + off) = v;
    }
}

// ---------------------------------------------------------------------------
// Kernel 1: QKV GEMM — m201 phase-interleaved schedule, RACE-FIXED.
// BM=128, BN=384 (x read once), BK=64, grid 256, 8 waves 2M x 4N (acc[4][6]).
// LDS 128KB: A 2x16K @0/16384, B 2x48K @32768/81920.
// Per tile, 2 phases: {10 ds_read ; 3 gload_lds(next tile) ; s_barrier ;
// lgkmcnt(0) ; setprio(1) ; 24 MFMA ; setprio(0) ; s_barrier}.
// Issue order per tile: G(t+1) x6 then A(t+2) x4 -> tile-end wait is
// vmcnt(4) PLACED BEFORE the releasing barrier (wait-then-barrier: each
// wave proves its OWN gloads landed, then the barrier releases readers —
// the R8 race is gone).  vmcnt drains to 0 only at tile 14.
// A pipeline is 2 tiles deep via named paA/paB register sets (rule #20).
// ---------------------------------------------------------------------------
__global__ __launch_bounds__(512, 2) void qkv_gemm(
    const float* __restrict__ x,
    const unsigned char* __restrict__ wt2,
    unsigned short* __restrict__ qo,
    unsigned short* __restrict__ ko,
    unsigned short* __restrict__ vto) {

    __shared__ char smem[131072];

    const int tid = threadIdx.x;
    const int bm  = blockIdx.x;               // 0..255
    const int lane = tid & 63, wid = tid >> 6;
    const int lm = lane & 15, l4 = lane >> 4;
    const int wm = wid >> 2, wn = wid & 3;

    f32x4 acc[4][6];
#pragma unroll
    for (int i = 0; i < 4; ++i)
#pragma unroll
        for (int j = 0; j < 6; ++j) acc[i][j] = (f32x4)0.f;

    // A staging: thread -> row tid>>2, 16 consecutive f32
    const int arow = tid >> 2;
    const int acb  = (tid & 3) * 16;
    const float* xp = x + (size_t)(bm * 128 + arow) * 1024 + acb;
    const int aswz = (arow & 7) << 4;
    const int aw0 = arow * 128 + ((acb * 2) ^ aswz);
    const int aw1 = arow * 128 + ((acb * 2 + 16) ^ aswz);

    // B staging: wave wid owns chunks wid*6..+5 (1KB each)
    const int ci0 = wid * 6;
    const unsigned char* wsrc = wt2 +
        (size_t)(wid * 48 + (lane >> 3)) * 128 + (lane & 7) * 16;

    int amr[4], bnr[6];
#pragma unroll
    for (int mi = 0; mi < 4; ++mi) amr[mi] = wm * 64 + mi * 16 + lm;
#pragma unroll
    for (int ni = 0; ni < 6; ++ni) bnr[ni] = wn * 96 + ni * 16 + lm;

    s16x8 af[4], bf[6];
    f32x4 pA0, pA1, pA2, pA3;   // A(t+1) on even-tile entry
    f32x4 pB0, pB1, pB2, pB3;   // A(t+1) on odd-tile entry

#define PHASE_READS(ABUF, BBUF, KOFF)                                          \
    do {                                                                       \
        _Pragma("unroll")                                                      \
        for (int mi = 0; mi < 4; ++mi)                                         \
            af[mi] = *(const s16x8*)(smem + (ABUF) + amr[mi] * 128 +           \
                      (((KOFF) + l4 * 16) ^ ((amr[mi] & 7) << 4)));            \
        _Pragma("unroll")                                                      \
        for (int ni = 0; ni < 6; ++ni)                                         \
            bf[ni] = *(const s16x8*)(smem + (BBUF) + bnr[ni] * 128 +           \
                      (((KOFF) + l4 * 16) ^ ((bnr[ni] & 7) << 4)));            \
    } while (0)

#define MFMA_CLUSTER()                                                         \
    do {                                                                       \
        __builtin_amdgcn_s_setprio(1);                                         \
        _Pragma("unroll")                                                      \
        for (int ni = 0; ni < 6; ++ni)                                         \
            _Pragma("unroll")                                                  \
            for (int mi = 0; mi < 4; ++mi)                                     \
                acc[mi][ni] = __builtin_amdgcn_mfma_f32_16x16x32_bf16(         \
                    af[mi], bf[ni], acc[mi][ni], 0, 0, 0);                     \
        __builtin_amdgcn_s_setprio(0);                                         \
    } while (0)

#define GSTAGE(TNEXT, BDST, C0)                                                \
    do {                                                                       \
        const unsigned char* ws_ = wsrc + (size_t)(TNEXT) * 49152;             \
        _Pragma("unroll")                                                      \
        for (int c = (C0); c < (C0) + 3; ++c)                                  \
            GLOAD_LDS16(ws_ + c * 1024, smem + (BDST) + (ci0 + c) * 1024);     \
    } while (0)

#define BAR() __builtin_amdgcn_s_barrier()
#define LGKM0() asm volatile("s_waitcnt lgkmcnt(0)" ::: "memory")

    // ---- prologue: A(0), G(0)->B[0], A(1)->paA; publish A(0) ----
    {
        f32x4 a0 = *(const f32x4*)(xp);
        f32x4 a1 = *(const f32x4*)(xp + 4);
        f32x4 a2 = *(const f32x4*)(xp + 8);
        f32x4 a3 = *(const f32x4*)(xp + 12);
        GSTAGE(0, 32768, 0);
        GSTAGE(0, 32768, 3);
        pA0 = *(const f32x4*)(xp + 64);
        pA1 = *(const f32x4*)(xp + 68);
        pA2 = *(const f32x4*)(xp + 72);
        pA3 = *(const f32x4*)(xp + 76);
        *(s16x8*)(smem + aw0) = cvt8(a0, a1);   // auto counted vmcnt
        *(s16x8*)(smem + aw1) = cvt8(a2, a3);
        asm volatile("s_waitcnt vmcnt(4)" ::: "memory");  // G(0) landed
        LGKM0();
        BAR();
    }

    for (int ti = 0; ti < 7; ++ti) {
        const int t = 2 * ti;
        // =========== EVEN tile t: read A[0],B[0]; stage -> A[1],B[1] =======
        PHASE_READS(0, 32768, 0);
        GSTAGE(t + 1, 81920, 0);
        BAR(); LGKM0();
        MFMA_CLUSTER();
        BAR();
        PHASE_READS(0, 32768, 64);
        GSTAGE(t + 1, 81920, 3);
        {   // issue A(t+2) -> paB
            const float* xq = xp + (t + 2) * 64;
            pB0 = *(const f32x4*)(xq);
            pB1 = *(const f32x4*)(xq + 4);
            pB2 = *(const f32x4*)(xq + 8);
            pB3 = *(const f32x4*)(xq + 12);
        }
        *(s16x8*)(smem + 16384 + aw0) = cvt8(pA0, pA1);   // A(t+1) -> A[1]
        *(s16x8*)(smem + 16384 + aw1) = cvt8(pA2, pA3);
        asm volatile("s_waitcnt vmcnt(4) lgkmcnt(0)" ::: "memory"); // G proven
        BAR();
        MFMA_CLUSTER();
        BAR();
        // =========== ODD tile t+1: read A[1],B[1]; stage -> A[0],B[0] ======
        PHASE_READS(16384, 81920, 0);
        GSTAGE(t + 2, 32768, 0);
        BAR(); LGKM0();
        MFMA_CLUSTER();
        BAR();
        PHASE_READS(16384, 81920, 64);
        GSTAGE(t + 2, 32768, 3);
        {   // issue A(t+3) -> paA
            const float* xq = xp + (t + 3) * 64;
            pA0 = *(const f32x4*)(xq);
            pA1 = *(const f32x4*)(xq + 4);
            pA2 = *(const f32x4*)(xq + 8);
            pA3 = *(const f32x4*)(xq + 12);
        }
        *(s16x8*)(smem + aw0) = cvt8(pB0, pB1);           // A(t+2) -> A[0]
        *(s16x8*)(smem + aw1) = cvt8(pB2, pB3);
        asm volatile("s_waitcnt vmcnt(4) lgkmcnt(0)" ::: "memory");
        BAR();
        MFMA_CLUSTER();
        BAR();
    }

    // =========== tile 14 (even): stage G(15)->B[1], A(15)=paA -> A[1] ======
    PHASE_READS(0, 32768, 0);
    GSTAGE(15, 81920, 0);
    BAR(); LGKM0();
    MFMA_CLUSTER();
    BAR();
    PHASE_READS(0, 32768, 64);
    GSTAGE(15, 81920, 3);
    *(s16x8*)(smem + 16384 + aw0) = cvt8(pA0, pA1);
    *(s16x8*)(smem + 16384 + aw1) = cvt8(pA2, pA3);
    asm volatile("s_waitcnt vmcnt(0) lgkmcnt(0)" ::: "memory");  // tail drain
    BAR();
    MFMA_CLUSTER();
    BAR();
    // =========== tile 15 (odd): compute only =========
    PHASE_READS(16384, 81920, 0);
    LGKM0();
    MFMA_CLUSTER();
    PHASE_READS(16384, 81920, 64);
    LGKM0();
    MFMA_CLUSTER();

#undef PHASE_READS
#undef MFMA_CLUSTER
#undef GSTAGE
#undef BAR
#undef LGKM0

    // ---- epilogue (verified R6) ----
#pragma unroll
    for (int mi = 0; mi < 4; ++mi) {
        int m0 = bm * 128 + wm * 64 + mi * 16 + l4 * 4;
#pragma unroll
        for (int ni = 0; ni < 6; ++ni) {
            int nb  = wn * 96 + ni * 16;
            int mat = nb >> 7;                 // 0=Q 1=K 2=V
            int col = (nb & 127) + lm;
            if (mat == 2) {
                int bb2 = m0 >> 8, tt = m0 & 255;
                s16x4 w4;
#pragma unroll
                for (int j = 0; j < 4; ++j) w4[j] = (short)f2bf(acc[mi][ni][j]);
                *(s16x4*)(vto + ((size_t)bb2 * 128 + col) * 256 + tt) = w4;
            } else {
                unsigned short* dst = (mat == 0) ? qo : ko;
#pragma unroll
                for (int j = 0; j < 4; ++j)
                    dst[(size_t)(m0 + j) * 128 + col] = f2bf(acc[mi][ni][j]);
            }
        }
    }
}

// ---------------------------------------------------------------------------
// Kernel 2: causal attention (unchanged, verified; ~7µs).
// ---------------------------------------------------------------------------
__global__ __launch_bounds__(512) void attn(
    const unsigned short* __restrict__ q,
    const unsigned short* __restrict__ k,
    const unsigned short* __restrict__ vt,
    float* __restrict__ out) {

    __shared__ char pbuf[65536];               // 8 waves x [16][256] bf16

    const int tid = threadIdx.x, wid = tid >> 6, lane = tid & 63;
    const int lm = lane & 15, l4 = lane >> 4;
    const int b = blockIdx.x >> 1, qt = blockIdx.x & 1;
    const int qbase = qt << 7;
    const int t0 = qbase + wid * 16;
    const int nfrags = (qbase + 128) >> 4;
    const int nkf    = (qbase + 128) >> 5;

    const unsigned short* qrow = q + (size_t)(b * 256 + t0 + lm) * 128 + l4 * 8;
    s16x8 qf[4];
#pragma unroll
    for (int kf = 0; kf < 4; ++kf) qf[kf] = *(const s16x8*)(qrow + kf * 32);

    f32x4 sacc[16];
#pragma unroll
    for (int i = 0; i < 16; ++i) sacc[i] = (f32x4)0.f;

    const unsigned short* kbase = k + (size_t)(b * 256) * 128 + l4 * 8;
#pragma unroll
    for (int nf = 0; nf < 16; ++nf) {
        if (nf < nfrags) {
#pragma unroll
            for (int kf = 0; kf < 4; ++kf) {
                s16x8 a = *(const s16x8*)(kbase + (size_t)(nf * 16 + lm) * 128 + kf * 32);
                sacc[nf] = __builtin_amdgcn_mfma_f32_16x16x32_bf16(a, qf[kf], sacc[nf], 0, 0, 0);
            }
        }
    }

    const float scale = 0.08838834764831845f;  // 1/sqrt(128)
    const int tg = t0 + lm;
    float mx = -1e30f;
#pragma unroll
    for (int nf = 0; nf < 16; ++nf) {
        if (nf < nfrags) {
#pragma unroll
            for (int j = 0; j < 4; ++j) {
                int kv = nf * 16 + l4 * 4 + j;
                float s = sacc[nf][j] * scale;
                s = (kv > tg) ? -1e30f : s;
                sacc[nf][j] = s;
                mx = fmaxf(mx, s);
            }
        }
    }
    mx = fmaxf(mx, __shfl_xor(mx, 16));
    mx = fmaxf(mx, __shfl_xor(mx, 32));
    float sum = 0.f;
#pragma unroll
    for (int nf = 0; nf < 16; ++nf) {
        if (nf < nfrags) {
#pragma unroll
            for (int j = 0; j < 4; ++j) {
                float p = __expf(sacc[nf][j] - mx);
                sacc[nf][j] = p;
                sum += p;
            }
        }
    }
    sum += __shfl_xor(sum, 16);
    sum += __shfl_xor(sum, 32);
    float rinv = 1.0f / sum;

    char* pw = pbuf + wid * 8192 + lm * 512;
#pragma unroll
    for (int nf = 0; nf < 16; ++nf) {
        if (nf < nfrags) {
            s16x4 w;
#pragma unroll
            for (int j = 0; j < 4; ++j) w[j] = (short)f2bf(sacc[nf][j] * rinv);
            *(s16x4*)(pw + ((nf * 32 + l4 * 8) ^ ((lm & 7) << 4))) = w;
        }
    }
    asm volatile("s_waitcnt lgkmcnt(0)" ::: "memory");

    f32x4 oacc[8];
#pragma unroll
    for (int i = 0; i < 8; ++i) oacc[i] = (f32x4)0.f;

    const unsigned short* vbase = vt + (size_t)b * 32768 + l4 * 8;
#pragma unroll
    for (int kvf = 0; kvf < 8; ++kvf) {
        if (kvf < nkf) {
            s16x8 pf = *(const s16x8*)(pbuf + wid * 8192 + lm * 512 +
                        ((kvf * 64 + l4 * 16) ^ ((lm & 7) << 4)));
#pragma unroll
            for (int hf = 0; hf < 8; ++hf) {
                s16x8 a = *(const s16x8*)(vbase + (size_t)(hf * 16 + lm) * 256 + kvf * 32);
                oacc[hf] = __builtin_amdgcn_mfma_f32_16x16x32_bf16(a, pf, oacc[hf], 0, 0, 0);
            }
        }
    }

    float* ob = out + (size_t)(b * 256 + t0 + lm) * 128 + l4 * 4;
#pragma unroll
    for (int hf = 0; hf < 8; ++hf)
        *(f32x4*)(ob + hf * 16) = oacc[hf];
}

// ---------------------------------------------------------------------------
extern "C" void kernel_launch(void* const* d_in, const int* in_sizes, int n_in,
                              void* d_out, int out_size, void* d_ws, size_t ws_size,
                              hipStream_t stream) {
    const float* x  = (const float*)d_in[0];
    const float* Wq = (const float*)d_in[1];
    const float* Wk = (const float*)d_in[2];
    const float* Wv = (const float*)d_in[3];
    float* out = (float*)d_out;

    char* ws = (char*)d_ws;
    unsigned char*  wt = (unsigned char*)(ws);                     // 786432 B (swizzle-tiled)
    unsigned short* qb = (unsigned short*)(ws + 786432);
    unsigned short* kb = (unsigned short*)(ws + 786432 + 8388608);
    unsigned short* vb = (unsigned short*)(ws + 786432 + 2 * 8388608);

    prep_wt<<<384, 256, 0, stream>>>(Wq, Wk, Wv, wt);
    qkv_gemm<<<256, 512, 0, stream>>>(x, wt, qb, kb, vb);
    attn<<<256, 512, 0, stream>>>(qb, kb, vb, out);
}

// Round 11
// 76.848 us; speedup vs baseline: 1.1655x; 1.1655x over previous
//
#include <hip/hip_runtime.h>

typedef float  f32x4  __attribute__((ext_vector_type(4)));
typedef short  s16x8  __attribute__((ext_vector_type(8)));
typedef short  s16x4  __attribute__((ext_vector_type(4)));

__device__ __forceinline__ unsigned short f2bf(float f) {
    unsigned int u = __float_as_uint(f);
    return (unsigned short)((u + 0x7FFFu + ((u >> 16) & 1u)) >> 16);
}

__device__ __forceinline__ s16x8 cvt8(f32x4 a, f32x4 b) {
    union { unsigned int u[4]; s16x8 v; } r;
    asm("v_cvt_pk_bf16_f32 %0, %1, %2" : "=v"(r.u[0]) : "v"(a[0]), "v"(a[1]));
    asm("v_cvt_pk_bf16_f32 %0, %1, %2" : "=v"(r.u[1]) : "v"(a[2]), "v"(a[3]));
    asm("v_cvt_pk_bf16_f32 %0, %1, %2" : "=v"(r.u[2]) : "v"(b[0]), "v"(b[1]));
    asm("v_cvt_pk_bf16_f32 %0, %1, %2" : "=v"(r.u[3]) : "v"(b[2]), "v"(b[3]));
    return r.v;
}

// lgkm-only barrier (vmcnt stays in flight)
__device__ __forceinline__ void lds_barrier() {
    asm volatile("s_waitcnt lgkmcnt(0)" ::: "memory");
    __builtin_amdgcn_s_barrier();
    asm volatile("" ::: "memory");
}

// ---------------------------------------------------------------------------
// Kernel 0: wt3 = FRAGMENT-MAJOR bf16 weights (verified R9).
// Fragment (n16,ks,kkk) = one wave's exact MFMA B-operand (64 lanes x 16B).
// value = W_sel[k][n&127], n = n16*16 + (lane&15),
// k = ks*64 + kkk*32 + (lane>>4)*8 + j; byte = fragid*1024 + lane*16 + j*2.
// ---------------------------------------------------------------------------
__global__ void prep_wt(const float* __restrict__ Wq,
                        const float* __restrict__ Wk,
                        const float* __restrict__ Wv,
                        unsigned char* __restrict__ wt3) {
    int n = blockIdx.x;                       // 0..383
    const float* W = (n < 128) ? Wq : ((n < 256) ? Wk : Wv);
    int h = n & 127;
    int n16 = n >> 4, lmn = n & 15;
    for (int k = threadIdx.x; k < 1024; k += blockDim.x) {
        unsigned short v = f2bf(W[(size_t)k * 128 + h]);
        int ks = k >> 6, rem = k & 63;
        int kkk = rem >> 5, l4_ = (rem >> 3) & 3, j = rem & 7;
        int lane = l4_ * 16 + lmn;
        size_t off = (size_t)(n16 * 32 + ks * 2 + kkk) * 1024 + lane * 16 + j * 2;
        *(unsigned short*)(wt3 + off) = v;
    }
}

// ---------------------------------------------------------------------------
// Kernel 1: QKV GEMM — VMEM-byte-minimal config on the R9-proven structure.
// Model (fits R2/R5/R9 exactly): chip VMEM streaming ceiling ~7.2 TB/s;
// time = total bytes / 7.2 TB/s.  BM=128, BN=384, grid 256 -> bytes =
// A 134MB + B 196MB + stores 25MB = 355MB -> 48us floor (vs 552MB/75us at
// BM=64).  B is wave-private REGISTERS from fragment-major wt3 (1 coalesced
// dwordx4 per fragment, zero duplication, zero LDS coupling, waits are
// compiler-counted per wave).  LDS holds only A (2x16KB swizzled dbuf),
// ONE lgkm-only barrier/tile.  B loads double-named (bqE/bqO) and issued a
// HALF-TILE after last use -> ~3K cy in flight >> HBM latency, so the
// 1-block/CU latency exposure that hurt R6/R7 is covered per-wave.
// 8 waves as 1M x 8N (wave = 128 rows x 48 cols, acc[8][3] = 96 VGPR).
// Outputs: Q,K bf16 [B*T][128]; V transposed bf16 [B][128][256].
// ---------------------------------------------------------------------------
__global__ __launch_bounds__(512, 2) void qkv_gemm(
    const float* __restrict__ x,
    const unsigned char* __restrict__ wt3,
    unsigned short* __restrict__ qo,
    unsigned short* __restrict__ ko,
    unsigned short* __restrict__ vto) {

    __shared__ char smem[32768];              // A: 2 x [128][128B] swizzled

    const int tid = threadIdx.x;
    const int bm  = blockIdx.x;               // 0..255 (M tiles of 128)
    const int lane = tid & 63, wid = tid >> 6;
    const int lm = lane & 15, l4 = lane >> 4;

    f32x4 acc[8][3];
#pragma unroll
    for (int i = 0; i < 8; ++i)
#pragma unroll
        for (int j = 0; j < 3; ++j) acc[i][j] = (f32x4)0.f;

    // ---- A staging: thread -> row tid>>2, 16 consecutive f32 ----
    const int ar  = tid >> 2;                 // 0..127
    const int acb = (tid & 3) * 16;
    const float* xp = x + (size_t)(bm * 128 + ar) * 1024 + acb;
    const int aswz = (ar & 7) << 4;
    const int aw0 = ar * 128 + ((acb * 2) ^ aswz);
    const int aw1 = ar * 128 + ((acb * 2 + 16) ^ aswz);

    // ---- B fragment pointers (wave-private) ----
    const unsigned char* wb = wt3 + (size_t)lane * 16;
    const unsigned char* wbq[3];
#pragma unroll
    for (int ni = 0; ni < 3; ++ni) wbq[ni] = wb + (size_t)(wid * 3 + ni) * 32768;

    int arow[8];
#pragma unroll
    for (int mi = 0; mi < 8; ++mi) arow[mi] = mi * 16 + lm;

    s16x8 af[8];
    s16x8 bqE0[3], bqE1[3], bqO0[3], bqO1[3];
    f32x4 pa0, pa1, pa2, pa3;

#define AFREAD(AB, KOFF)                                                       \
    do {                                                                       \
        _Pragma("unroll")                                                      \
        for (int mi = 0; mi < 8; ++mi)                                         \
            af[mi] = *(const s16x8*)(smem + (AB) + arow[mi] * 128 +            \
                      (((KOFF) + l4 * 16) ^ ((arow[mi] & 7) << 4)));           \
    } while (0)

#define MFMA3(BQ)                                                              \
    do {                                                                       \
        __builtin_amdgcn_s_setprio(1);                                         \
        _Pragma("unroll")                                                      \
        for (int ni = 0; ni < 3; ++ni)                                         \
            _Pragma("unroll")                                                  \
            for (int mi = 0; mi < 8; ++mi)                                     \
                acc[mi][ni] = __builtin_amdgcn_mfma_f32_16x16x32_bf16(         \
                    af[mi], (BQ)[ni], acc[mi][ni], 0, 0, 0);                   \
        __builtin_amdgcn_s_setprio(0);                                         \
    } while (0)

    // ---- prologue: A(0)->LDS buf0, B(0)->bqE, pa=A(1) ----
    {
        f32x4 a0 = *(const f32x4*)(xp);
        f32x4 a1 = *(const f32x4*)(xp + 4);
        f32x4 a2 = *(const f32x4*)(xp + 8);
        f32x4 a3 = *(const f32x4*)(xp + 12);
#pragma unroll
        for (int ni = 0; ni < 3; ++ni) {
            bqE0[ni] = *(const s16x8*)(wbq[ni]);
            bqE1[ni] = *(const s16x8*)(wbq[ni] + 1024);
        }
        *(s16x8*)(smem + aw0) = cvt8(a0, a1);
        *(s16x8*)(smem + aw1) = cvt8(a2, a3);
        pa0 = *(const f32x4*)(xp + 64);
        pa1 = *(const f32x4*)(xp + 68);
        pa2 = *(const f32x4*)(xp + 72);
        pa3 = *(const f32x4*)(xp + 76);
        lds_barrier();
    }

    for (int tp = 0; tp < 8; ++tp) {
        const int t = tp * 2;
        // ============ EVEN tile t (A buf0) ============
        AFREAD(0, 0);
        MFMA3(bqE0);
        // issue B(t+1) kkk0 (used next tile start: ~3K cy in flight)
#pragma unroll
        for (int ni = 0; ni < 3; ++ni)
            bqO0[ni] = *(const s16x8*)(wbq[ni] + (t + 1) * 2048);
        AFREAD(0, 64);
        MFMA3(bqE1);
#pragma unroll
        for (int ni = 0; ni < 3; ++ni)
            bqO1[ni] = *(const s16x8*)(wbq[ni] + (t + 1) * 2048 + 1024);
        // stage A(t+1) -> buf1; pa = A(t+2)
        *(s16x8*)(smem + 16384 + aw0) = cvt8(pa0, pa1);
        *(s16x8*)(smem + 16384 + aw1) = cvt8(pa2, pa3);
        if (tp < 7) {
            const float* xq = xp + (t + 2) * 64;
            pa0 = *(const f32x4*)(xq);
            pa1 = *(const f32x4*)(xq + 4);
            pa2 = *(const f32x4*)(xq + 8);
            pa3 = *(const f32x4*)(xq + 12);
        }
        lds_barrier();

        // ============ ODD tile t+1 (A buf1) ============
        AFREAD(16384, 0);
        MFMA3(bqO0);
        if (tp < 7) {
#pragma unroll
            for (int ni = 0; ni < 3; ++ni)
                bqE0[ni] = *(const s16x8*)(wbq[ni] + (t + 2) * 2048);
        }
        AFREAD(16384, 64);
        MFMA3(bqO1);
        if (tp < 7) {
#pragma unroll
            for (int ni = 0; ni < 3; ++ni)
                bqE1[ni] = *(const s16x8*)(wbq[ni] + (t + 2) * 2048 + 1024);
            // stage A(t+2) -> buf0; pa = A(t+3)
            *(s16x8*)(smem + aw0) = cvt8(pa0, pa1);
            *(s16x8*)(smem + aw1) = cvt8(pa2, pa3);
            const float* xq = xp + (t + 3) * 64;
            pa0 = *(const f32x4*)(xq);
            pa1 = *(const f32x4*)(xq + 4);
            pa2 = *(const f32x4*)(xq + 8);
            pa3 = *(const f32x4*)(xq + 12);
            lds_barrier();
        }
    }

#undef AFREAD
#undef MFMA3

    // ---- epilogue (layout verified R6-R9) ----
#pragma unroll
    for (int mi = 0; mi < 8; ++mi) {
        int m0 = bm * 128 + mi * 16 + l4 * 4;  // global row (j adds 0..3)
#pragma unroll
        for (int ni = 0; ni < 3; ++ni) {
            int nb  = wid * 48 + ni * 16;
            int mat = nb >> 7;                 // 0=Q 1=K 2=V
            int col = (nb & 127) + lm;
            if (mat == 2) {
                int bb2 = m0 >> 8, tt = m0 & 255;
                s16x4 w4;
#pragma unroll
                for (int j = 0; j < 4; ++j) w4[j] = (short)f2bf(acc[mi][ni][j]);
                *(s16x4*)(vto + ((size_t)bb2 * 128 + col) * 256 + tt) = w4;
            } else {
                unsigned short* dst = (mat == 0) ? qo : ko;
#pragma unroll
                for (int j = 0; j < 4; ++j)
                    dst[(size_t)(m0 + j) * 128 + col] = f2bf(acc[mi][ni][j]);
            }
        }
    }
}

// ---------------------------------------------------------------------------
// Kernel 2: causal attention (unchanged, verified; ~7µs).
// ---------------------------------------------------------------------------
__global__ __launch_bounds__(512) void attn(
    const unsigned short* __restrict__ q,
    const unsigned short* __restrict__ k,
    const unsigned short* __restrict__ vt,
    float* __restrict__ out) {

    __shared__ char pbuf[65536];               // 8 waves x [16][256] bf16

    const int tid = threadIdx.x, wid = tid >> 6, lane = tid & 63;
    const int lm = lane & 15, l4 = lane >> 4;
    const int b = blockIdx.x >> 1, qt = blockIdx.x & 1;
    const int qbase = qt << 7;
    const int t0 = qbase + wid * 16;
    const int nfrags = (qbase + 128) >> 4;
    const int nkf    = (qbase + 128) >> 5;

    const unsigned short* qrow = q + (size_t)(b * 256 + t0 + lm) * 128 + l4 * 8;
    s16x8 qf[4];
#pragma unroll
    for (int kf = 0; kf < 4; ++kf) qf[kf] = *(const s16x8*)(qrow + kf * 32);

    f32x4 sacc[16];
#pragma unroll
    for (int i = 0; i < 16; ++i) sacc[i] = (f32x4)0.f;

    const unsigned short* kbase = k + (size_t)(b * 256) * 128 + l4 * 8;
#pragma unroll
    for (int nf = 0; nf < 16; ++nf) {
        if (nf < nfrags) {
#pragma unroll
            for (int kf = 0; kf < 4; ++kf) {
                s16x8 a = *(const s16x8*)(kbase + (size_t)(nf * 16 + lm) * 128 + kf * 32);
                sacc[nf] = __builtin_amdgcn_mfma_f32_16x16x32_bf16(a, qf[kf], sacc[nf], 0, 0, 0);
            }
        }
    }

    const float scale = 0.08838834764831845f;  // 1/sqrt(128)
    const int tg = t0 + lm;
    float mx = -1e30f;
#pragma unroll
    for (int nf = 0; nf < 16; ++nf) {
        if (nf < nfrags) {
#pragma unroll
            for (int j = 0; j < 4; ++j) {
                int kv = nf * 16 + l4 * 4 + j;
                float s = sacc[nf][j] * scale;
                s = (kv > tg) ? -1e30f : s;
                sacc[nf][j] = s;
                mx = fmaxf(mx, s);
            }
        }
    }
    mx = fmaxf(mx, __shfl_xor(mx, 16));
    mx = fmaxf(mx, __shfl_xor(mx, 32));
    float sum = 0.f;
#pragma unroll
    for (int nf = 0; nf < 16; ++nf) {
        if (nf < nfrags) {
#pragma unroll
            for (int j = 0; j < 4; ++j) {
                float p = __expf(sacc[nf][j] - mx);
                sacc[nf][j] = p;
                sum += p;
            }
        }
    }
    sum += __shfl_xor(sum, 16);
    sum += __shfl_xor(sum, 32);
    float rinv = 1.0f / sum;

    char* pw = pbuf + wid * 8192 + lm * 512;
#pragma unroll
    for (int nf = 0; nf < 16; ++nf) {
        if (nf < nfrags) {
            s16x4 w;
#pragma unroll
            for (int j = 0; j < 4; ++j) w[j] = (short)f2bf(sacc[nf][j] * rinv);
            *(s16x4*)(pw + ((nf * 32 + l4 * 8) ^ ((lm & 7) << 4))) = w;
        }
    }
    asm volatile("s_waitcnt lgkmcnt(0)" ::: "memory");

    f32x4 oacc[8];
#pragma unroll
    for (int i = 0; i < 8; ++i) oacc[i] = (f32x4)0.f;

    const unsigned short* vbase = vt + (size_t)b * 32768 + l4 * 8;
#pragma unroll
    for (int kvf = 0; kvf < 8; ++kvf) {
        if (kvf < nkf) {
            s16x8 pf = *(const s16x8*)(pbuf + wid * 8192 + lm * 512 +
                        ((kvf * 64 + l4 * 16) ^ ((lm & 7) << 4)));
#pragma unroll
            for (int hf = 0; hf < 8; ++hf) {
                s16x8 a = *(const s16x8*)(vbase + (size_t)(hf * 16 + lm) * 256 + kvf * 32);
                oacc[hf] = __builtin_amdgcn_mfma_f32_16x16x32_bf16(a, pf, oacc[hf], 0, 0, 0);
            }
        }
    }

    float* ob = out + (size_t)(b * 256 + t0 + lm) * 128 + l4 * 4;
#pragma unroll
    for (int hf = 0; hf < 8; ++hf)
        *(f32x4*)(ob + hf * 16) = oacc[hf];
}

// ---------------------------------------------------------------------------
extern "C" void kernel_launch(void* const* d_in, const int* in_sizes, int n_in,
                              void* d_out, int out_size, void* d_ws, size_t ws_size,
                              hipStream_t stream) {
    const float* x  = (const float*)d_in[0];
    const float* Wq = (const float*)d_in[1];
    const float* Wk = (const float*)d_in[2];
    const float* Wv = (const float*)d_in[3];
    float* out = (float*)d_out;

    char* ws = (char*)d_ws;
    unsigned char*  wt = (unsigned char*)(ws);                     // 786432 B (fragment-major)
    unsigned short* qb = (unsigned short*)(ws + 786432);
    unsigned short* kb = (unsigned short*)(ws + 786432 + 8388608);
    unsigned short* vb = (unsigned short*)(ws + 786432 + 2 * 8388608);

    prep_wt<<<384, 256, 0, stream>>>(Wq, Wk, Wv, wt);
    qkv_gemm<<<256, 512, 0, stream>>>(x, wt, qb, kb, vb);
    attn<<<256, 512, 0, stream>>>(qb, kb, vb, out);
}